// Round 1
// baseline (336.216 us; speedup 1.0000x reference)
//
#include <hip/hip_runtime.h>
#include <math.h>

#define N 512
#define C 16
#define NLAYERS 4
#define AGG_IN 1028   // N + (NLAYERS + N)

// One layer transition. Block q computes a_next[q]; thread p handles edge (q,p).
__global__ __launch_bounds__(512) void dan_layer_kernel(
    const float* __restrict__ a_in,    // [N]
    float*       __restrict__ a_out,   // [N]
    const float* __restrict__ vec_W,   // [LT,N,N,C]
    const float* __restrict__ vec_b,   // [LT,N,N,C]
    const float* __restrict__ syn_W1,  // [LT,N,N,3,C]
    const float* __restrict__ syn_b1,  // [LT,N,N,3]
    const float* __restrict__ syn_W2,  // [LT,N,N,3]
    const float* __restrict__ syn_b2,  // [LT,N,N]
    const float* __restrict__ agg_W1,  // [LT,N,3,AGG_IN]
    const float* __restrict__ agg_b1,  // [LT,N,3]
    const float* __restrict__ agg_W2,  // [LT,N,3]
    const float* __restrict__ agg_b2,  // [LT,N]
    int l, int reverse_out)
{
    const int q = blockIdx.x;
    const int p = threadIdx.x;

    __shared__ float red[3][8];   // per-wave partials for the 3 agg dots

    const size_t edge = ((size_t)(l * N + q)) * N + p;
    const float av = a_in[p];

    // ---- Single_VEC: filtered[c] = tanh(a[p]*W + b), c = 0..15 ----
    const float4* vW = (const float4*)(vec_W + edge * C);
    const float4* vB = (const float4*)(vec_b + edge * C);
    float f[16];
    #pragma unroll
    for (int j = 0; j < 4; ++j) {
        float4 w = vW[j];
        float4 b = vB[j];
        f[4*j+0] = tanhf(fmaf(av, w.x, b.x));
        f[4*j+1] = tanhf(fmaf(av, w.y, b.y));
        f[4*j+2] = tanhf(fmaf(av, w.z, b.z));
        f[4*j+3] = tanhf(fmaf(av, w.w, b.w));
    }

    // ---- Single_Synapse: h1[o] = tanh(dot16 + b1), s = tanh(dot3 + b2) ----
    const float4* sW1 = (const float4*)(syn_W1 + edge * 48);
    float h1[3];
    #pragma unroll
    for (int o = 0; o < 3; ++o) {
        float acc = syn_b1[edge * 3 + o];
        #pragma unroll
        for (int j = 0; j < 4; ++j) {
            float4 w = sW1[o * 4 + j];
            acc = fmaf(w.x, f[4*j+0], acc);
            acc = fmaf(w.y, f[4*j+1], acc);
            acc = fmaf(w.z, f[4*j+2], acc);
            acc = fmaf(w.w, f[4*j+3], acc);
        }
        h1[o] = tanhf(acc);
    }
    float s = syn_b2[edge];
    s = fmaf(syn_W2[edge*3+0], h1[0], s);
    s = fmaf(syn_W2[edge*3+1], h1[1], s);
    s = fmaf(syn_W2[edge*3+2], h1[2], s);
    s = tanhf(s);

    // ---- Node_Aggregator: 3 dot-512s over s (thread p holds s[q,p]) ----
    const float* aW1 = agg_W1 + ((size_t)(l * N + q)) * 3 * AGG_IN;
    float part0 = aW1[0 * AGG_IN + p] * s;
    float part1 = aW1[1 * AGG_IN + p] * s;
    float part2 = aW1[2 * AGG_IN + p] * s;

    // wave-64 butterfly reduce
    #pragma unroll
    for (int off = 32; off > 0; off >>= 1) {
        part0 += __shfl_down(part0, off, 64);
        part1 += __shfl_down(part1, off, 64);
        part2 += __shfl_down(part2, off, 64);
    }
    const int wave = threadIdx.x >> 6;
    if ((threadIdx.x & 63) == 0) {
        red[0][wave] = part0;
        red[1][wave] = part1;
        red[2][wave] = part2;
    }
    __syncthreads();

    if (threadIdx.x == 0) {
        float h[3];
        #pragma unroll
        for (int k = 0; k < 3; ++k) {
            float acc = 0.f;
            #pragma unroll
            for (int w = 0; w < 8; ++w) acc += red[k][w];
            // lcode one-hot at column N + (l+1); node one-hot at N + NLAYERS + q
            acc += aW1[k * AGG_IN + N + (l + 1)];
            acc += aW1[k * AGG_IN + N + NLAYERS + q];
            acc += agg_b1[((size_t)(l * N + q)) * 3 + k];
            h[k] = tanhf(acc);
        }
        const float* aW2 = agg_W2 + ((size_t)(l * N + q)) * 3;
        float out = agg_b2[l * N + q];
        out = fmaf(aW2[0], h[0], out);
        out = fmaf(aW2[1], h[1], out);
        out = fmaf(aW2[2], h[2], out);
        if (reverse_out) a_out[N - 1 - q] = out;
        else             a_out[q] = out;
    }
}

extern "C" void kernel_launch(void* const* d_in, const int* in_sizes, int n_in,
                              void* d_out, int out_size, void* d_ws, size_t ws_size,
                              hipStream_t stream) {
    const float* x      = (const float*)d_in[0];
    const float* vec_W  = (const float*)d_in[1];
    const float* vec_b  = (const float*)d_in[2];
    const float* syn_W1 = (const float*)d_in[3];
    const float* syn_b1 = (const float*)d_in[4];
    const float* syn_W2 = (const float*)d_in[5];
    const float* syn_b2 = (const float*)d_in[6];
    const float* agg_W1 = (const float*)d_in[7];
    const float* agg_b1 = (const float*)d_in[8];
    const float* agg_W2 = (const float*)d_in[9];
    const float* agg_b2 = (const float*)d_in[10];
    float* out = (float*)d_out;

    float* a0 = (float*)d_ws;        // [N] activation after layer 0
    float* a1 = a0 + N;              // [N] activation after layer 1

    dan_layer_kernel<<<N, N, 0, stream>>>(x,  a0,  vec_W, vec_b, syn_W1, syn_b1,
                                          syn_W2, syn_b2, agg_W1, agg_b1, agg_W2, agg_b2,
                                          0, 0);
    dan_layer_kernel<<<N, N, 0, stream>>>(a0, a1,  vec_W, vec_b, syn_W1, syn_b1,
                                          syn_W2, syn_b2, agg_W1, agg_b1, agg_W2, agg_b2,
                                          1, 0);
    dan_layer_kernel<<<N, N, 0, stream>>>(a1, out, vec_W, vec_b, syn_W1, syn_b1,
                                          syn_W2, syn_b2, agg_W1, agg_b1, agg_W2, agg_b2,
                                          2, 1);
}

// Round 2
// 331.288 us; speedup vs baseline: 1.0149x; 1.0149x over previous
//
#include <hip/hip_runtime.h>
#include <math.h>

#define N 512
#define C 16
#define NLAYERS 4
#define AGG_IN 1028   // N + (NLAYERS + N)

// Branchless tanh: tanh(x) = sign(x) * (1 - t) / (1 + t), t = exp(-2|x|).
// t in (0,1] -> no overflow/NaN; underflow for |x|>44 gives exactly 1.0.
// Single basic block => compiler can hoist global loads across it.
__device__ __forceinline__ float fast_tanh(float x) {
    float ax = fabsf(x);
    float t  = __expf(-2.0f * ax);              // v_mul + v_exp_f32
    float r  = __fdividef(1.0f - t, 1.0f + t);  // v_rcp_f32 + mul
    return copysignf(r, x);                     // v_bfi
}

// One layer transition. Block q computes a_next[q]; thread p handles edge (q,p).
// __launch_bounds__(512, 4): 4 waves/SIMD min => VGPR<=128 => 2 blocks/CU resident.
__global__ __launch_bounds__(512, 4) void dan_layer_kernel(
    const float* __restrict__ a_in,    // [N]
    float*       __restrict__ a_out,   // [N]
    const float* __restrict__ vec_W,   // [LT,N,N,C]
    const float* __restrict__ vec_b,   // [LT,N,N,C]
    const float* __restrict__ syn_W1,  // [LT,N,N,3,C]
    const float* __restrict__ syn_b1,  // [LT,N,N,3]
    const float* __restrict__ syn_W2,  // [LT,N,N,3]
    const float* __restrict__ syn_b2,  // [LT,N,N]
    const float* __restrict__ agg_W1,  // [LT,N,3,AGG_IN]
    const float* __restrict__ agg_b1,  // [LT,N,3]
    const float* __restrict__ agg_W2,  // [LT,N,3]
    const float* __restrict__ agg_b2,  // [LT,N]
    int l, int reverse_out)
{
    const int q = blockIdx.x;
    const int p = threadIdx.x;

    __shared__ float red[3][8];   // per-wave partials for the 3 agg dots

    const size_t edge = ((size_t)(l * N + q)) * N + p;
    const float av = a_in[p];

    // ---- Issue the big weight loads up front (branchless body lets these
    //      all stay in flight while earlier results are consumed) ----
    const float4* vW  = (const float4*)(vec_W + edge * C);
    const float4* vB  = (const float4*)(vec_b + edge * C);
    const float4* sW1 = (const float4*)(syn_W1 + edge * 48);

    float4 w0 = vW[0], w1 = vW[1], w2 = vW[2], w3 = vW[3];
    float4 b0 = vB[0], b1 = vB[1], b2 = vB[2], b3 = vB[3];

    float sb1_0 = syn_b1[edge * 3 + 0];
    float sb1_1 = syn_b1[edge * 3 + 1];
    float sb1_2 = syn_b1[edge * 3 + 2];
    float sw2_0 = syn_W2[edge * 3 + 0];
    float sw2_1 = syn_W2[edge * 3 + 1];
    float sw2_2 = syn_W2[edge * 3 + 2];
    float sb2   = syn_b2[edge];

    const float* aW1 = agg_W1 + ((size_t)(l * N + q)) * 3 * AGG_IN;
    float a0 = aW1[0 * AGG_IN + p];
    float a1 = aW1[1 * AGG_IN + p];
    float a2 = aW1[2 * AGG_IN + p];

    // ---- Single_VEC: filtered[c] = tanh(a[p]*W + b) ----
    float f[16];
    f[ 0] = fast_tanh(fmaf(av, w0.x, b0.x));
    f[ 1] = fast_tanh(fmaf(av, w0.y, b0.y));
    f[ 2] = fast_tanh(fmaf(av, w0.z, b0.z));
    f[ 3] = fast_tanh(fmaf(av, w0.w, b0.w));
    f[ 4] = fast_tanh(fmaf(av, w1.x, b1.x));
    f[ 5] = fast_tanh(fmaf(av, w1.y, b1.y));
    f[ 6] = fast_tanh(fmaf(av, w1.z, b1.z));
    f[ 7] = fast_tanh(fmaf(av, w1.w, b1.w));
    f[ 8] = fast_tanh(fmaf(av, w2.x, b2.x));
    f[ 9] = fast_tanh(fmaf(av, w2.y, b2.y));
    f[10] = fast_tanh(fmaf(av, w2.z, b2.z));
    f[11] = fast_tanh(fmaf(av, w2.w, b2.w));
    f[12] = fast_tanh(fmaf(av, w3.x, b3.x));
    f[13] = fast_tanh(fmaf(av, w3.y, b3.y));
    f[14] = fast_tanh(fmaf(av, w3.z, b3.z));
    f[15] = fast_tanh(fmaf(av, w3.w, b3.w));

    // ---- Single_Synapse: h1[o] = tanh(dot16 + b1), s = tanh(dot3 + b2) ----
    float h1[3];
    float sb1v[3] = {sb1_0, sb1_1, sb1_2};
    #pragma unroll
    for (int o = 0; o < 3; ++o) {
        float acc = sb1v[o];
        #pragma unroll
        for (int j = 0; j < 4; ++j) {
            float4 w = sW1[o * 4 + j];
            acc = fmaf(w.x, f[4*j+0], acc);
            acc = fmaf(w.y, f[4*j+1], acc);
            acc = fmaf(w.z, f[4*j+2], acc);
            acc = fmaf(w.w, f[4*j+3], acc);
        }
        h1[o] = fast_tanh(acc);
    }
    float s = sb2;
    s = fmaf(sw2_0, h1[0], s);
    s = fmaf(sw2_1, h1[1], s);
    s = fmaf(sw2_2, h1[2], s);
    s = fast_tanh(s);

    // ---- Node_Aggregator partials: thread p holds s[q,p] ----
    float part0 = a0 * s;
    float part1 = a1 * s;
    float part2 = a2 * s;

    // wave-64 reduce
    #pragma unroll
    for (int off = 32; off > 0; off >>= 1) {
        part0 += __shfl_down(part0, off, 64);
        part1 += __shfl_down(part1, off, 64);
        part2 += __shfl_down(part2, off, 64);
    }
    const int wave = threadIdx.x >> 6;
    if ((threadIdx.x & 63) == 0) {
        red[0][wave] = part0;
        red[1][wave] = part1;
        red[2][wave] = part2;
    }
    __syncthreads();

    if (threadIdx.x == 0) {
        float h[3];
        #pragma unroll
        for (int k = 0; k < 3; ++k) {
            float acc = 0.f;
            #pragma unroll
            for (int w = 0; w < 8; ++w) acc += red[k][w];
            // lcode one-hot at column N + (l+1); node one-hot at N + NLAYERS + q
            acc += aW1[k * AGG_IN + N + (l + 1)];
            acc += aW1[k * AGG_IN + N + NLAYERS + q];
            acc += agg_b1[((size_t)(l * N + q)) * 3 + k];
            h[k] = fast_tanh(acc);
        }
        const float* aW2 = agg_W2 + ((size_t)(l * N + q)) * 3;
        float out = agg_b2[l * N + q];
        out = fmaf(aW2[0], h[0], out);
        out = fmaf(aW2[1], h[1], out);
        out = fmaf(aW2[2], h[2], out);
        if (reverse_out) a_out[N - 1 - q] = out;
        else             a_out[q] = out;
    }
}

extern "C" void kernel_launch(void* const* d_in, const int* in_sizes, int n_in,
                              void* d_out, int out_size, void* d_ws, size_t ws_size,
                              hipStream_t stream) {
    const float* x      = (const float*)d_in[0];
    const float* vec_W  = (const float*)d_in[1];
    const float* vec_b  = (const float*)d_in[2];
    const float* syn_W1 = (const float*)d_in[3];
    const float* syn_b1 = (const float*)d_in[4];
    const float* syn_W2 = (const float*)d_in[5];
    const float* syn_b2 = (const float*)d_in[6];
    const float* agg_W1 = (const float*)d_in[7];
    const float* agg_b1 = (const float*)d_in[8];
    const float* agg_W2 = (const float*)d_in[9];
    const float* agg_b2 = (const float*)d_in[10];
    float* out = (float*)d_out;

    float* a0 = (float*)d_ws;        // [N] activation after layer 0
    float* a1 = a0 + N;              // [N] activation after layer 1

    dan_layer_kernel<<<N, N, 0, stream>>>(x,  a0,  vec_W, vec_b, syn_W1, syn_b1,
                                          syn_W2, syn_b2, agg_W1, agg_b1, agg_W2, agg_b2,
                                          0, 0);
    dan_layer_kernel<<<N, N, 0, stream>>>(a0, a1,  vec_W, vec_b, syn_W1, syn_b1,
                                          syn_W2, syn_b2, agg_W1, agg_b1, agg_W2, agg_b2,
                                          1, 0);
    dan_layer_kernel<<<N, N, 0, stream>>>(a1, out, vec_W, vec_b, syn_W1, syn_b1,
                                          syn_W2, syn_b2, agg_W1, agg_b1, agg_W2, agg_b2,
                                          2, 1);
}